// Round 5
// baseline (1608.405 us; speedup 1.0000x reference)
//
#include <hip/hip_runtime.h>
#include <hip/hip_bf16.h>

#define NPT     16384
#define NQ      512
#define NS      32
#define BATCH   8
#define CHUNKS  8          // blocks per batch for FPS
#define FPS_TPB 256
#define CPTS    (NPT / CHUNKS)   // 2048 points per block

typedef float f32x2 __attribute__((ext_vector_type(2)));

// ---------------------------------------------------------------------------
// Packed fp32 math via explicit VOP3P asm (v_pk_*_f32). Round-to-nearest per
// half — bit-exact vs scalar v_add/v_mul. Subtraction via x + (-p).
// ---------------------------------------------------------------------------
__device__ inline f32x2 pk_add(f32x2 a, f32x2 b)
{
    f32x2 d;
    asm("v_pk_add_f32 %0, %1, %2" : "=v"(d) : "v"(a), "v"(b));
    return d;
}
__device__ inline f32x2 pk_mul(f32x2 a, f32x2 b)
{
    f32x2 d;
    asm("v_pk_mul_f32 %0, %1, %2" : "=v"(d) : "v"(a), "v"(b));
    return d;
}

// ---------------------------------------------------------------------------
// DPP helper on a 64-bit value (two 32-bit halves), invalid lanes -> 0.
// Keys are (dist_bits<<32)|~idx, always > 0 and finite as f64 patterns, so
// v_max_f64 == exact u64 max (positive doubles: value order == bit order).
// ---------------------------------------------------------------------------
template <int CTRL>
__device__ inline double dpp_f64(double x)
{
    const unsigned long long u = (unsigned long long)__double_as_longlong(x);
    int lo = (int)(unsigned)u;
    int hi = (int)(unsigned)(u >> 32);
    lo = __builtin_amdgcn_update_dpp(0, lo, CTRL, 0xf, 0xf, true);
    hi = __builtin_amdgcn_update_dpp(0, hi, CTRL, 0xf, 0xf, true);
    return __longlong_as_double(
        (long long)(((unsigned long long)(unsigned)hi << 32) | (unsigned)lo));
}

// ---------------------------------------------------------------------------
// Kernel 1: furthest point sampling, 8 blocks per batch (64 total, all
// co-resident). Each block owns 2048 contiguous points: 8 pts/thread =
// 16 VGPRs of state -> no AGPR pressure. Per step: packed local update ->
// DPP wave max -> LDS cross-wave -> device-scope atomicMax(u64 key) +
// arrival counter spin -> LDS broadcast. Global index in the key keeps the
// first-occurrence tie-break exact across blocks.
// ---------------------------------------------------------------------------
__global__ __launch_bounds__(FPS_TPB, 1)
void fps_kernel(const float* __restrict__ xyz, float* __restrict__ new_xyz,
                unsigned long long* __restrict__ gkey, unsigned* __restrict__ gcnt)
{
#pragma clang fp contract(off)
    const int blk = blockIdx.x;
    const int b   = blk >> 3;
    const int c   = blk & 7;
    const int t   = threadIdx.x;
    const float* xb = xyz + (size_t)b * NPT * 3;
    const int base = c * CPTS;

    f32x2 xr[4], yr[4], zr[4], dr[4];
    const float INF = __int_as_float(0x7f800000);
#pragma unroll
    for (int j = 0; j < 4; ++j) {
        const int p0 = base + (2 * j) * FPS_TPB + t;
        const int p1 = base + (2 * j + 1) * FPS_TPB + t;
        xr[j] = (f32x2){xb[p0 * 3 + 0], xb[p1 * 3 + 0]};
        yr[j] = (f32x2){xb[p0 * 3 + 1], xb[p1 * 3 + 1]};
        zr[j] = (f32x2){xb[p0 * 3 + 2], xb[p1 * 3 + 2]};
        dr[j] = (f32x2){INF, INF};
    }

    __shared__ unsigned long long red[4];
    __shared__ unsigned long long bc;

    unsigned long long* gk = gkey + (size_t)b * NQ;
    unsigned*           gc = gcnt + (size_t)b * NQ;

    float px = xb[0], py = xb[1], pz = xb[2];

    for (int s = 0; s < NQ; ++s) {
        if (c == 0 && t == 0) {
            float* o = new_xyz + ((size_t)b * NQ + s) * 3;
            o[0] = px; o[1] = py; o[2] = pz;
        }
        if (s == NQ - 1) break;

        // --- packed distance update + local argmax over 8 points ----------
        const float nx = -px, ny = -py, nz = -pz;
        const f32x2 npx = {nx, nx}, npy = {ny, ny}, npz = {nz, nz};
        float dmax = -1.0f;
        int   bi_  = 0;
#pragma unroll
        for (int j = 0; j < 4; ++j) {
            const f32x2 dx = pk_add(xr[j], npx);
            const f32x2 dy = pk_add(yr[j], npy);
            const f32x2 dz = pk_add(zr[j], npz);
            f32x2 d = pk_add(pk_mul(dx, dx), pk_mul(dy, dy));
            d = pk_add(d, pk_mul(dz, dz));
            f32x2 dn;
            dn.x = fminf(dr[j].x, d.x);
            dn.y = fminf(dr[j].y, d.y);
            dr[j] = dn;
            // within pair: .x has the smaller global index -> wins ties
            const float ds = fmaxf(dn.x, dn.y);
            const int   is = (dn.x >= dn.y) ? (2 * j) : (2 * j + 1);
            // ascending j, strict > keeps first occurrence
            if (ds > dmax) { dmax = ds; bi_ = is; }
        }

        const unsigned pidx = (unsigned)(base + bi_ * FPS_TPB + t);
        double kd = __longlong_as_double((long long)(
            ((unsigned long long)__float_as_uint(dmax) << 32) | (unsigned)(~pidx)));

        // --- wave max via DPP; lane 63 = wave max -------------------------
        kd = fmax(kd, dpp_f64<0x111>(kd));   // row_shr:1
        kd = fmax(kd, dpp_f64<0x112>(kd));   // row_shr:2
        kd = fmax(kd, dpp_f64<0x114>(kd));   // row_shr:4
        kd = fmax(kd, dpp_f64<0x118>(kd));   // row_shr:8
        kd = fmax(kd, dpp_f64<0x142>(kd));   // row_bcast:15
        kd = fmax(kd, dpp_f64<0x143>(kd));   // row_bcast:31

        if ((t & 63) == 63)
            red[t >> 6] = (unsigned long long)__double_as_longlong(kd);
        __syncthreads();

        // --- cross-wave (4 slots) + cross-block combine -------------------
        if (t == 0) {
            unsigned long long kb = red[0];
            for (int w = 1; w < 4; ++w) { const unsigned long long o = red[w]; if (o > kb) kb = o; }
            __hip_atomic_fetch_max(&gk[s], kb, __ATOMIC_RELAXED, __HIP_MEMORY_SCOPE_AGENT);
            __hip_atomic_fetch_add(&gc[s], 1u, __ATOMIC_ACQ_REL, __HIP_MEMORY_SCOPE_AGENT);
            while (__hip_atomic_load(&gc[s], __ATOMIC_ACQUIRE, __HIP_MEMORY_SCOPE_AGENT) < CHUNKS) { }
            bc = __hip_atomic_load(&gk[s], __ATOMIC_ACQUIRE, __HIP_MEMORY_SCOPE_AGENT);
        }
        __syncthreads();

        const int nxt = (int)(unsigned)(~(unsigned)bc);   // block-uniform
        px = xb[nxt * 3 + 0];
        py = xb[nxt * 3 + 1];
        pz = xb[nxt * 3 + 2];
        __syncthreads();   // protect bc before next step's overwrite
    }
}

// ---------------------------------------------------------------------------
// Kernel 2: ball query. One wave per (b,s) query; ascending index scan with
// ballot + prefix popcount collects exactly the 32 smallest in-radius indices.
// ---------------------------------------------------------------------------
__global__ __launch_bounds__(256) void bq_kernel(const float* __restrict__ xyz,
                                                 const float* __restrict__ newxyz,
                                                 int* __restrict__ gidx)
{
    const int wid  = (blockIdx.x * 256 + threadIdx.x) >> 6;  // 0..4095
    const int lane = threadIdx.x & 63;
    const int b    = wid >> 9;
    const float* xb = xyz + (size_t)b * NPT * 3;

    const float qx = newxyz[wid * 3 + 0];
    const float qy = newxyz[wid * 3 + 1];
    const float qz = newxyz[wid * 3 + 2];
    int* out = gidx + (size_t)wid * NS;

    const float R2 = 0.04f;   // f32(0.2*0.2 in f64); NOT 0.2f*0.2f (1 ulp higher)
    int cnt = 0, first = -1;

    for (int base = 0; base < NPT; base += 64) {
        const int p = base + lane;
        const float dx = __fsub_rn(xb[p * 3 + 0], qx);
        const float dy = __fsub_rn(xb[p * 3 + 1], qy);
        const float dz = __fsub_rn(xb[p * 3 + 2], qz);
        const float d  = __fadd_rn(__fadd_rn(__fmul_rn(dx, dx), __fmul_rn(dy, dy)),
                                   __fmul_rn(dz, dz));
        const bool in = (d <= R2);
        const unsigned long long m = __ballot(in);
        if (first < 0 && m) first = base + (__ffsll((unsigned long long)m) - 1);
        if (in) {
            const int pos = cnt + __popcll(m & ((1ull << lane) - 1ull));
            if (pos < NS) out[pos] = p;
        }
        cnt += __popcll(m);
        if (cnt >= NS) break;
    }
    if (cnt < NS) {
        const int f = (cnt > 0) ? first : (NPT - 1);
        for (int j = cnt + lane; j < NS; j += 64) out[j] = f;
    }
}

// ---------------------------------------------------------------------------
// Kernel 3: gather + 3-layer MLP (BN folded) + max over the 32 samples.
// One block per (b,s). Weights staged per-layer in a shared 34.8KB region.
// Channel layout permuted: [feat(64) | xyz-diff(3) | pad] for aligned float4.
// ---------------------------------------------------------------------------
template <int OP>
__device__ inline void mlp_layer(const float* __restrict__ inb,
                                 const float* __restrict__ wbuf,
                                 const float* __restrict__ scp,
                                 const float* __restrict__ bip,
                                 float* __restrict__ outb, int nchunk, int t)
{
    const int ko = t & 15;
    const int og = t >> 4;
    const int o0 = og * OP;
    float acc0[OP], acc1[OP];
#pragma unroll
    for (int j = 0; j < OP; ++j) { acc0[j] = 0.f; acc1[j] = 0.f; }

    for (int cc = 0; cc < nchunk; ++cc) {
        const int c = cc * 4;
        const float4 xa = *(const float4*)(inb + ko * 68 + c);
        const float4 xb = *(const float4*)(inb + (ko + 16) * 68 + c);
#pragma unroll
        for (int j = 0; j < OP; ++j) {
            const float4 w = *(const float4*)(wbuf + (o0 + j) * 68 + c);
            acc0[j] += xa.x * w.x + xa.y * w.y + xa.z * w.z + xa.w * w.w;
            acc1[j] += xb.x * w.x + xb.y * w.y + xb.z * w.z + xb.w * w.w;
        }
    }
#pragma unroll
    for (int j = 0; j < OP; ++j) {
        const float sv = scp[o0 + j], bv = bip[o0 + j];
        acc0[j] = fmaxf(acc0[j] * sv + bv, 0.f);
        acc1[j] = fmaxf(acc1[j] * sv + bv, 0.f);
    }
#pragma unroll
    for (int jb = 0; jb < OP; jb += 4) {
        *(float4*)(outb + ko * 68 + o0 + jb) =
            make_float4(acc0[jb], acc0[jb + 1], acc0[jb + 2], acc0[jb + 3]);
        *(float4*)(outb + (ko + 16) * 68 + o0 + jb) =
            make_float4(acc1[jb], acc1[jb + 1], acc1[jb + 2], acc1[jb + 3]);
    }
}

__device__ inline void mlp_layer2(const float* __restrict__ inb,
                                  const float* __restrict__ wbuf,
                                  const float* __restrict__ scp,
                                  const float* __restrict__ bip,
                                  float* __restrict__ out, int b, int s, int t)
{
    const int ko = t & 15;
    const int og = t >> 4;
    const int o0 = og * 8;
    float acc0[8], acc1[8];
#pragma unroll
    for (int j = 0; j < 8; ++j) { acc0[j] = 0.f; acc1[j] = 0.f; }

    for (int cc = 0; cc < 16; ++cc) {
        const int c = cc * 4;
        const float4 xa = *(const float4*)(inb + ko * 68 + c);
        const float4 xb = *(const float4*)(inb + (ko + 16) * 68 + c);
#pragma unroll
        for (int j = 0; j < 8; ++j) {
            const float4 w = *(const float4*)(wbuf + (o0 + j) * 68 + c);
            acc0[j] += xa.x * w.x + xa.y * w.y + xa.z * w.z + xa.w * w.w;
            acc1[j] += xb.x * w.x + xb.y * w.y + xb.z * w.z + xb.w * w.w;
        }
    }
    float v[8];
#pragma unroll
    for (int j = 0; j < 8; ++j) {
        const float sv = scp[o0 + j], bv = bip[o0 + j];
        const float h0 = fmaxf(acc0[j] * sv + bv, 0.f);
        const float h1 = fmaxf(acc1[j] * sv + bv, 0.f);
        v[j] = fmaxf(h0, h1);
    }
#pragma unroll
    for (int m = 1; m <= 8; m <<= 1) {
#pragma unroll
        for (int j = 0; j < 8; ++j) v[j] = fmaxf(v[j], __shfl_xor(v[j], m, 64));
    }
    if (ko == 0) {
#pragma unroll
        for (int j = 0; j < 8; ++j)
            out[((size_t)b * 128 + o0 + j) * NQ + s] = v[j];
    }
}

__global__ __launch_bounds__(256) void mlp_kernel(
    const float* __restrict__ xyz, const float* __restrict__ feat,
    const float* __restrict__ newxyz, const int* __restrict__ gidx,
    const float* __restrict__ w0, const float* __restrict__ g0,
    const float* __restrict__ b0, const float* __restrict__ m0,
    const float* __restrict__ v0,
    const float* __restrict__ w1, const float* __restrict__ g1,
    const float* __restrict__ b1, const float* __restrict__ m1,
    const float* __restrict__ v1,
    const float* __restrict__ w2, const float* __restrict__ g2,
    const float* __restrict__ b2, const float* __restrict__ m2,
    const float* __restrict__ v2,
    float* __restrict__ out)
{
    __shared__ float wbuf[128 * 68];   // 34816 B
    __shared__ float bufA[32 * 68];    //  8704 B
    __shared__ float bufB[32 * 68];    //  8704 B
    __shared__ float sc[256], bi[256]; //  2048 B   -> total 54272 B

    const int t   = threadIdx.x;
    const int grp = blockIdx.x;       // 0..4095
    const int b   = grp >> 9;
    const int s   = grp & (NQ - 1);
    const int* gi = gidx + (size_t)grp * NS;

    // folded BN params for all three layers
    if (t < 64) {
        const float sv = g0[t] * rsqrtf(v0[t] + 1e-5f);
        sc[t] = sv; bi[t] = b0[t] - m0[t] * sv;
    } else if (t < 128) {
        const int j = t - 64;
        const float sv = g1[j] * rsqrtf(v1[j] + 1e-5f);
        sc[t] = sv; bi[t] = b1[j] - m1[j] * sv;
    } else {
        const int j = t - 128;
        const float sv = g2[j] * rsqrtf(v2[j] + 1e-5f);
        sc[t] = sv; bi[t] = b2[j] - m2[j] * sv;
    }

    // layer-0 weights, channel-permuted: [feat 0..63 | xyz 64..66 | 0]
    for (int i = t; i < 64 * 68; i += 256) {
        const int o = i / 68, c = i - o * 68;
        float v;
        if (c < 64)       v = w0[o * 67 + 3 + c];
        else if (c < 67)  v = w0[o * 67 + (c - 64)];
        else              v = 0.f;
        wbuf[i] = v;
    }

    // gather x into bufA: feat then xyz-diff
    {
        const int k = t >> 3, f = t & 7;
        const int p = gi[k];
        const float* fr = feat + ((size_t)b * NPT + p) * 64 + f * 8;
        const float4 a0 = *(const float4*)fr;
        const float4 a1 = *(const float4*)(fr + 4);
        *(float4*)(bufA + k * 68 + f * 8)     = a0;
        *(float4*)(bufA + k * 68 + f * 8 + 4) = a1;
        if (f == 0) {
            const float qx = newxyz[grp * 3 + 0];
            const float qy = newxyz[grp * 3 + 1];
            const float qz = newxyz[grp * 3 + 2];
            const float* xp = xyz + ((size_t)b * NPT + p) * 3;
            bufA[k * 68 + 64] = xp[0] - qx;
            bufA[k * 68 + 65] = xp[1] - qy;
            bufA[k * 68 + 66] = xp[2] - qz;
            bufA[k * 68 + 67] = 0.f;
        }
    }
    __syncthreads();

    mlp_layer<4>(bufA, wbuf, sc, bi, bufB, 17, t);
    __syncthreads();

    for (int i = t; i < 64 * 68; i += 256) {
        const int o = i / 68, c = i - o * 68;
        wbuf[i] = (c < 64) ? w1[o * 64 + c] : 0.f;
    }
    __syncthreads();

    mlp_layer<4>(bufB, wbuf, sc + 64, bi + 64, bufA, 16, t);
    __syncthreads();

    for (int i = t; i < 128 * 68; i += 256) {
        const int o = i / 68, c = i - o * 68;
        wbuf[i] = (c < 64) ? w2[o * 64 + c] : 0.f;
    }
    __syncthreads();

    mlp_layer2(bufA, wbuf, sc + 128, bi + 128, out, b, s, t);
}

// ---------------------------------------------------------------------------
extern "C" void kernel_launch(void* const* d_in, const int* in_sizes, int n_in,
                              void* d_out, int out_size, void* d_ws, size_t ws_size,
                              hipStream_t stream)
{
    const float* xyz  = (const float*)d_in[0];
    const float* feat = (const float*)d_in[1];
    const float* w0 = (const float*)d_in[2];
    const float* g0 = (const float*)d_in[3];
    const float* b0 = (const float*)d_in[4];
    const float* m0 = (const float*)d_in[5];
    const float* v0 = (const float*)d_in[6];
    const float* w1 = (const float*)d_in[7];
    const float* g1 = (const float*)d_in[8];
    const float* b1 = (const float*)d_in[9];
    const float* m1 = (const float*)d_in[10];
    const float* v1 = (const float*)d_in[11];
    const float* w2 = (const float*)d_in[12];
    const float* g2 = (const float*)d_in[13];
    const float* b2 = (const float*)d_in[14];
    const float* m2 = (const float*)d_in[15];
    const float* v2 = (const float*)d_in[16];

    float* out      = (float*)d_out;
    float* new_xyz  = out;                      // 8*512*3 = 12288 floats
    float* out_feat = out + BATCH * NQ * 3;     // 8*128*512 floats

    // workspace layout
    int*   gidx = (int*)d_ws;                                   // 524288 B
    char*  syncbase = (char*)d_ws + 4096 * NS * sizeof(int);
    unsigned long long* gkey = (unsigned long long*)syncbase;   // 8*512*8 = 32768 B
    unsigned* gcnt = (unsigned*)(syncbase + BATCH * NQ * 8);    // 8*512*4 = 16384 B

    // zero the cross-block sync region (ws is re-poisoned before every launch)
    hipMemsetAsync(syncbase, 0, BATCH * NQ * 12, stream);

    fps_kernel<<<BATCH * CHUNKS, FPS_TPB, 0, stream>>>(xyz, new_xyz, gkey, gcnt);
    bq_kernel<<<(BATCH * NQ * 64) / 256, 256, 0, stream>>>(xyz, new_xyz, gidx);
    mlp_kernel<<<BATCH * NQ, 256, 0, stream>>>(xyz, feat, new_xyz, gidx,
                                               w0, g0, b0, m0, v0,
                                               w1, g1, b1, m1, v1,
                                               w2, g2, b2, m2, v2,
                                               out_feat);
}

// Round 6
// 1601.017 us; speedup vs baseline: 1.0046x; 1.0046x over previous
//
#include <hip/hip_runtime.h>
#include <hip/hip_bf16.h>

#define NPT   16384
#define NQ    512
#define NS    32
#define BATCH 8
#define NW    16          // waves per fps block
#define PPT   16          // points per thread (fps)

// ---------------------------------------------------------------------------
// DPP helper on a 64-bit value (two 32-bit halves), invalid lanes -> 0.
// Keys are (dist_bits<<32)|~orig_idx: always positive/finite as f64 patterns,
// so v_max_f64 == exact u64 max (positive doubles: value order == bit order).
// ---------------------------------------------------------------------------
template <int CTRL>
__device__ inline double dpp_f64(double x)
{
    const unsigned long long u = (unsigned long long)__double_as_longlong(x);
    int lo = (int)(unsigned)u;
    int hi = (int)(unsigned)(u >> 32);
    lo = __builtin_amdgcn_update_dpp(0, lo, CTRL, 0xf, 0xf, true);
    hi = __builtin_amdgcn_update_dpp(0, hi, CTRL, 0xf, 0xf, true);
    return __longlong_as_double(
        (long long)(((unsigned long long)(unsigned)hi << 32) | (unsigned)lo));
}

__device__ inline unsigned long long d2u(double d)
{
    return (unsigned long long)__double_as_longlong(d);
}

// ---------------------------------------------------------------------------
// Kernel 0: Morton grid sort (8x8x8 = 512 cells), one block per batch.
// Writes sorted SoA copies (exact fp32 copies) + original indices to ws.
// Intra-cell order is nondeterministic (LDS atomics) — harmless: all
// downstream math keys on the ORIGINAL index.
// ---------------------------------------------------------------------------
__device__ inline int spread3(int v)
{
    return (v & 1) | ((v & 2) << 2) | ((v & 4) << 4);
}

__global__ __launch_bounds__(1024) void sort_kernel(
    const float* __restrict__ xyz,
    float* __restrict__ sx, float* __restrict__ sy, float* __restrict__ sz,
    int* __restrict__ sorig)
{
    const int b = blockIdx.x;
    const int t = threadIdx.x;
    const float* xb = xyz + (size_t)b * NPT * 3;

    __shared__ unsigned hist[512];
    __shared__ unsigned cur[512];

    if (t < 512) hist[t] = 0;
    __syncthreads();

    for (int j = 0; j < PPT; ++j) {
        const int p = j * 1024 + t;
        const float x = xb[p * 3 + 0], y = xb[p * 3 + 1], z = xb[p * 3 + 2];
        int ix = (int)(x * 8.0f), iy = (int)(y * 8.0f), iz = (int)(z * 8.0f);
        ix = min(max(ix, 0), 7); iy = min(max(iy, 0), 7); iz = min(max(iz, 0), 7);
        const int cell = spread3(ix) | (spread3(iy) << 1) | (spread3(iz) << 2);
        atomicAdd(&hist[cell], 1u);
    }
    __syncthreads();

    const unsigned cnt = (t < 512) ? hist[t] : 0;
    for (int off = 1; off < 512; off <<= 1) {
        unsigned u = 0;
        if (t < 512 && t >= off) u = hist[t - off];
        __syncthreads();
        if (t < 512) hist[t] += u;
        __syncthreads();
    }
    if (t < 512) cur[t] = hist[t] - cnt;   // exclusive start offset
    __syncthreads();

    float* sxb = sx + (size_t)b * NPT;
    float* syb = sy + (size_t)b * NPT;
    float* szb = sz + (size_t)b * NPT;
    int*   sob = sorig + (size_t)b * NPT;

    for (int j = 0; j < PPT; ++j) {
        const int p = j * 1024 + t;
        const float x = xb[p * 3 + 0], y = xb[p * 3 + 1], z = xb[p * 3 + 2];
        int ix = (int)(x * 8.0f), iy = (int)(y * 8.0f), iz = (int)(z * 8.0f);
        ix = min(max(ix, 0), 7); iy = min(max(iy, 0), 7); iz = min(max(iz, 0), 7);
        const int cell = spread3(ix) | (spread3(iy) << 1) | (spread3(iz) << 2);
        const unsigned pos = atomicAdd(&cur[cell], 1u);
        sxb[pos] = x; syb[pos] = y; szb[pos] = z; sob[pos] = p;
    }
}

// ---------------------------------------------------------------------------
// Kernel 1: FPS with exact bbox pruning. One block per batch, 1024 threads.
// Wave w owns 1024 spatially-local sorted points; per thread: only d[16] is
// loop-carried in registers — coords/indices are re-loaded from the sorted
// (L2-resident) arrays only when the wave is ACTIVE. A wave skips a step iff
// mindist^2(pick, wave bbox) >= ub*(1+1e-5) (ub = its cached max dist): then
// provably no d changed, so the cached (key, argpos) stays exact.
// ---------------------------------------------------------------------------
__global__ __launch_bounds__(1024)
__attribute__((amdgpu_waves_per_eu(4, 4)))
void fps_kernel(const float* __restrict__ xyz,
                const float* __restrict__ sx, const float* __restrict__ sy,
                const float* __restrict__ sz, const int* __restrict__ sorig,
                float* __restrict__ new_xyz)
{
#pragma clang fp contract(off)
    const int b    = blockIdx.x;
    const int t    = threadIdx.x;
    const int w    = t >> 6;
    const int lane = t & 63;

    const float* xb  = xyz + (size_t)b * NPT * 3;
    const float* sxb = sx + (size_t)b * NPT;
    const float* syb = sy + (size_t)b * NPT;
    const float* szb = sz + (size_t)b * NPT;
    const int*   sob = sorig + (size_t)b * NPT;

    const int mybase = w * 1024 + lane * PPT;

    __shared__ unsigned long long red[NW];
    __shared__ int   wpos[NW];
    __shared__ float bbox[NW][6];    // xlo,xhi,ylo,yhi,zlo,zhi
    __shared__ float bcx, bcy, bcz;

    const float INF = __int_as_float(0x7f800000);

    // ---- init: load own coords once to build the wave bbox ----------------
    {
        float mnx = INF, mxx = -INF, mny = INF, mxy = -INF, mnz = INF, mxz = -INF;
        const float4* PX = (const float4*)(sxb + mybase);
        const float4* PY = (const float4*)(syb + mybase);
        const float4* PZ = (const float4*)(szb + mybase);
#pragma unroll
        for (int g = 0; g < 4; ++g) {
            const float4 X = PX[g], Y = PY[g], Z = PZ[g];
            mnx = fminf(mnx, fminf(fminf(X.x, X.y), fminf(X.z, X.w)));
            mxx = fmaxf(mxx, fmaxf(fmaxf(X.x, X.y), fmaxf(X.z, X.w)));
            mny = fminf(mny, fminf(fminf(Y.x, Y.y), fminf(Y.z, Y.w)));
            mxy = fmaxf(mxy, fmaxf(fmaxf(Y.x, Y.y), fmaxf(Y.z, Y.w)));
            mnz = fminf(mnz, fminf(fminf(Z.x, Z.y), fminf(Z.z, Z.w)));
            mxz = fmaxf(mxz, fmaxf(fmaxf(Z.x, Z.y), fmaxf(Z.z, Z.w)));
        }
#pragma unroll
        for (int off = 1; off < 64; off <<= 1) {
            mnx = fminf(mnx, __shfl_xor(mnx, off, 64));
            mxx = fmaxf(mxx, __shfl_xor(mxx, off, 64));
            mny = fminf(mny, __shfl_xor(mny, off, 64));
            mxy = fmaxf(mxy, __shfl_xor(mxy, off, 64));
            mnz = fminf(mnz, __shfl_xor(mnz, off, 64));
            mxz = fmaxf(mxz, __shfl_xor(mxz, off, 64));
        }
        if (lane == 0) {
            bbox[w][0] = mnx; bbox[w][1] = mxx;
            bbox[w][2] = mny; bbox[w][3] = mxy;
            bbox[w][4] = mnz; bbox[w][5] = mxz;
            red[w]  = (unsigned long long)0x7f800000ull << 32;  // ub = inf
            wpos[w] = mybase;
        }
    }
    __syncthreads();

    float d[PPT];
#pragma unroll
    for (int j = 0; j < PPT; ++j) d[j] = INF;

    float px = xb[0], py = xb[1], pz = xb[2];

    for (int s = 0; s < NQ; ++s) {
        if (t == 0) {
            float* o = new_xyz + ((size_t)b * NQ + s) * 3;
            o[0] = px; o[1] = py; o[2] = pz;
        }
        if (s == NQ - 1) break;

        // ---- skip test (wave-uniform): mindist^2(pick, bbox) vs cached ub -
        const float ub = __uint_as_float((unsigned)(red[w] >> 32));
        float ddx = fmaxf(fmaxf(bbox[w][0] - px, px - bbox[w][1]), 0.0f);
        float ddy = fmaxf(fmaxf(bbox[w][2] - py, py - bbox[w][3]), 0.0f);
        float ddz = fmaxf(fmaxf(bbox[w][4] - pz, pz - bbox[w][5]), 0.0f);
        const float m2 = ddx * ddx + ddy * ddy + ddz * ddz;
        const bool active = !(m2 >= ub * 1.00002f);

        if (active) {
            const float4* PX = (const float4*)(sxb + mybase);
            const float4* PY = (const float4*)(syb + mybase);
            const float4* PZ = (const float4*)(szb + mybase);
            const int4*   PO = (const int4*)(sob + mybase);

            unsigned long long kbest = 0;
            int pbest = mybase;
#pragma unroll
            for (int g = 0; g < 4; ++g) {
                const float4 X = PX[g], Y = PY[g], Z = PZ[g];
                const int4   O = PO[g];
                const float xs[4] = {X.x, X.y, X.z, X.w};
                const float ys[4] = {Y.x, Y.y, Y.z, Y.w};
                const float zs[4] = {Z.x, Z.y, Z.z, Z.w};
                const int   os[4] = {O.x, O.y, O.z, O.w};
#pragma unroll
                for (int k = 0; k < 4; ++k) {
                    const int j = g * 4 + k;
                    const float dx = __fsub_rn(xs[k], px);
                    const float dy = __fsub_rn(ys[k], py);
                    const float dz = __fsub_rn(zs[k], pz);
                    const float d2 = __fadd_rn(
                        __fadd_rn(__fmul_rn(dx, dx), __fmul_rn(dy, dy)),
                        __fmul_rn(dz, dz));
                    const float dn = fminf(d[j], d2);
                    d[j] = dn;
                    const unsigned long long key =
                        ((unsigned long long)__float_as_uint(dn) << 32) |
                        (unsigned)(~(unsigned)os[k]);
                    if (key > kbest) { kbest = key; pbest = mybase + j; }
                }
            }

            // wave max via DPP; lane 63 holds the wave max
            double kd = __longlong_as_double((long long)kbest);
            kd = fmax(kd, dpp_f64<0x111>(kd));   // row_shr:1
            kd = fmax(kd, dpp_f64<0x112>(kd));   // row_shr:2
            kd = fmax(kd, dpp_f64<0x114>(kd));   // row_shr:4
            kd = fmax(kd, dpp_f64<0x118>(kd));   // row_shr:8
            kd = fmax(kd, dpp_f64<0x142>(kd));   // row_bcast:15
            kd = fmax(kd, dpp_f64<0x143>(kd));   // row_bcast:31

            const unsigned long long u = d2u(kd);
            const int klo = __builtin_amdgcn_readlane((int)(unsigned)u, 63);
            const int khi = __builtin_amdgcn_readlane((int)(unsigned)(u >> 32), 63);
            const unsigned long long kmax =
                ((unsigned long long)(unsigned)khi << 32) | (unsigned)klo;

            const unsigned long long eqm = __ballot(kbest == kmax);
            const int wl = __ffsll(eqm) - 1;           // exactly one lane (keys unique)
            const int posw = __shfl(pbest, wl, 64);
            if (lane == 0) { red[w] = kmax; wpos[w] = posw; }
        }
        __syncthreads();

        // ---- block combine + next-pick coord fetch (thread 0) -------------
        if (t == 0) {
            unsigned long long best = red[0];
            int wi = 0;
#pragma unroll
            for (int ww = 1; ww < NW; ++ww) {
                const unsigned long long o = red[ww];
                if (o > best) { best = o; wi = ww; }
            }
            const int p = wpos[wi];
            bcx = sxb[p]; bcy = syb[p]; bcz = szb[p];
        }
        __syncthreads();

        px = bcx; py = bcy; pz = bcz;
    }
}

// ---------------------------------------------------------------------------
// Kernel 2: ball query. One wave per (b,s) query; ascending index scan with
// ballot + prefix popcount collects exactly the 32 smallest in-radius indices.
// ---------------------------------------------------------------------------
__global__ __launch_bounds__(256) void bq_kernel(const float* __restrict__ xyz,
                                                 const float* __restrict__ newxyz,
                                                 int* __restrict__ gidx)
{
    const int wid  = (blockIdx.x * 256 + threadIdx.x) >> 6;  // 0..4095
    const int lane = threadIdx.x & 63;
    const int b    = wid >> 9;
    const float* xb = xyz + (size_t)b * NPT * 3;

    const float qx = newxyz[wid * 3 + 0];
    const float qy = newxyz[wid * 3 + 1];
    const float qz = newxyz[wid * 3 + 2];
    int* out = gidx + (size_t)wid * NS;

    const float R2 = 0.04f;   // f32(0.2*0.2 in f64); NOT 0.2f*0.2f (1 ulp higher)
    int cnt = 0, first = -1;

    for (int base = 0; base < NPT; base += 64) {
        const int p = base + lane;
        const float dx = __fsub_rn(xb[p * 3 + 0], qx);
        const float dy = __fsub_rn(xb[p * 3 + 1], qy);
        const float dz = __fsub_rn(xb[p * 3 + 2], qz);
        const float d  = __fadd_rn(__fadd_rn(__fmul_rn(dx, dx), __fmul_rn(dy, dy)),
                                   __fmul_rn(dz, dz));
        const bool in = (d <= R2);
        const unsigned long long m = __ballot(in);
        if (first < 0 && m) first = base + (__ffsll((unsigned long long)m) - 1);
        if (in) {
            const int pos = cnt + __popcll(m & ((1ull << lane) - 1ull));
            if (pos < NS) out[pos] = p;
        }
        cnt += __popcll(m);
        if (cnt >= NS) break;
    }
    if (cnt < NS) {
        const int f = (cnt > 0) ? first : (NPT - 1);
        for (int j = cnt + lane; j < NS; j += 64) out[j] = f;
    }
}

// ---------------------------------------------------------------------------
// Kernel 3: gather + 3-layer MLP (BN folded) + max over the 32 samples.
// One block per (b,s). Weights staged per-layer in a shared 34.8KB region.
// Channel layout permuted: [feat(64) | xyz-diff(3) | pad] for aligned float4.
// ---------------------------------------------------------------------------
template <int OP>
__device__ inline void mlp_layer(const float* __restrict__ inb,
                                 const float* __restrict__ wbuf,
                                 const float* __restrict__ scp,
                                 const float* __restrict__ bip,
                                 float* __restrict__ outb, int nchunk, int t)
{
    const int ko = t & 15;
    const int og = t >> 4;
    const int o0 = og * OP;
    float acc0[OP], acc1[OP];
#pragma unroll
    for (int j = 0; j < OP; ++j) { acc0[j] = 0.f; acc1[j] = 0.f; }

    for (int cc = 0; cc < nchunk; ++cc) {
        const int c = cc * 4;
        const float4 xa = *(const float4*)(inb + ko * 68 + c);
        const float4 xb = *(const float4*)(inb + (ko + 16) * 68 + c);
#pragma unroll
        for (int j = 0; j < OP; ++j) {
            const float4 w = *(const float4*)(wbuf + (o0 + j) * 68 + c);
            acc0[j] += xa.x * w.x + xa.y * w.y + xa.z * w.z + xa.w * w.w;
            acc1[j] += xb.x * w.x + xb.y * w.y + xb.z * w.z + xb.w * w.w;
        }
    }
#pragma unroll
    for (int j = 0; j < OP; ++j) {
        const float sv = scp[o0 + j], bv = bip[o0 + j];
        acc0[j] = fmaxf(acc0[j] * sv + bv, 0.f);
        acc1[j] = fmaxf(acc1[j] * sv + bv, 0.f);
    }
#pragma unroll
    for (int jb = 0; jb < OP; jb += 4) {
        *(float4*)(outb + ko * 68 + o0 + jb) =
            make_float4(acc0[jb], acc0[jb + 1], acc0[jb + 2], acc0[jb + 3]);
        *(float4*)(outb + (ko + 16) * 68 + o0 + jb) =
            make_float4(acc1[jb], acc1[jb + 1], acc1[jb + 2], acc1[jb + 3]);
    }
}

__device__ inline void mlp_layer2(const float* __restrict__ inb,
                                  const float* __restrict__ wbuf,
                                  const float* __restrict__ scp,
                                  const float* __restrict__ bip,
                                  float* __restrict__ out, int b, int s, int t)
{
    const int ko = t & 15;
    const int og = t >> 4;
    const int o0 = og * 8;
    float acc0[8], acc1[8];
#pragma unroll
    for (int j = 0; j < 8; ++j) { acc0[j] = 0.f; acc1[j] = 0.f; }

    for (int cc = 0; cc < 16; ++cc) {
        const int c = cc * 4;
        const float4 xa = *(const float4*)(inb + ko * 68 + c);
        const float4 xb = *(const float4*)(inb + (ko + 16) * 68 + c);
#pragma unroll
        for (int j = 0; j < 8; ++j) {
            const float4 w = *(const float4*)(wbuf + (o0 + j) * 68 + c);
            acc0[j] += xa.x * w.x + xa.y * w.y + xa.z * w.z + xa.w * w.w;
            acc1[j] += xb.x * w.x + xb.y * w.y + xb.z * w.z + xb.w * w.w;
        }
    }
    float v[8];
#pragma unroll
    for (int j = 0; j < 8; ++j) {
        const float sv = scp[o0 + j], bv = bip[o0 + j];
        const float h0 = fmaxf(acc0[j] * sv + bv, 0.f);
        const float h1 = fmaxf(acc1[j] * sv + bv, 0.f);
        v[j] = fmaxf(h0, h1);
    }
#pragma unroll
    for (int m = 1; m <= 8; m <<= 1) {
#pragma unroll
        for (int j = 0; j < 8; ++j) v[j] = fmaxf(v[j], __shfl_xor(v[j], m, 64));
    }
    if (ko == 0) {
#pragma unroll
        for (int j = 0; j < 8; ++j)
            out[((size_t)b * 128 + o0 + j) * NQ + s] = v[j];
    }
}

__global__ __launch_bounds__(256) void mlp_kernel(
    const float* __restrict__ xyz, const float* __restrict__ feat,
    const float* __restrict__ newxyz, const int* __restrict__ gidx,
    const float* __restrict__ w0, const float* __restrict__ g0,
    const float* __restrict__ b0, const float* __restrict__ m0,
    const float* __restrict__ v0,
    const float* __restrict__ w1, const float* __restrict__ g1,
    const float* __restrict__ b1, const float* __restrict__ m1,
    const float* __restrict__ v1,
    const float* __restrict__ w2, const float* __restrict__ g2,
    const float* __restrict__ b2, const float* __restrict__ m2,
    const float* __restrict__ v2,
    float* __restrict__ out)
{
    __shared__ float wbuf[128 * 68];   // 34816 B
    __shared__ float bufA[32 * 68];    //  8704 B
    __shared__ float bufB[32 * 68];    //  8704 B
    __shared__ float sc[256], bi[256]; //  2048 B   -> total 54272 B

    const int t   = threadIdx.x;
    const int grp = blockIdx.x;       // 0..4095
    const int b   = grp >> 9;
    const int s   = grp & (NQ - 1);
    const int* gi = gidx + (size_t)grp * NS;

    // folded BN params for all three layers
    if (t < 64) {
        const float sv = g0[t] * rsqrtf(v0[t] + 1e-5f);
        sc[t] = sv; bi[t] = b0[t] - m0[t] * sv;
    } else if (t < 128) {
        const int j = t - 64;
        const float sv = g1[j] * rsqrtf(v1[j] + 1e-5f);
        sc[t] = sv; bi[t] = b1[j] - m1[j] * sv;
    } else {
        const int j = t - 128;
        const float sv = g2[j] * rsqrtf(v2[j] + 1e-5f);
        sc[t] = sv; bi[t] = b2[j] - m2[j] * sv;
    }

    // layer-0 weights, channel-permuted: [feat 0..63 | xyz 64..66 | 0]
    for (int i = t; i < 64 * 68; i += 256) {
        const int o = i / 68, c = i - o * 68;
        float v;
        if (c < 64)       v = w0[o * 67 + 3 + c];
        else if (c < 67)  v = w0[o * 67 + (c - 64)];
        else              v = 0.f;
        wbuf[i] = v;
    }

    // gather x into bufA: feat then xyz-diff
    {
        const int k = t >> 3, f = t & 7;
        const int p = gi[k];
        const float* fr = feat + ((size_t)b * NPT + p) * 64 + f * 8;
        const float4 a0 = *(const float4*)fr;
        const float4 a1 = *(const float4*)(fr + 4);
        *(float4*)(bufA + k * 68 + f * 8)     = a0;
        *(float4*)(bufA + k * 68 + f * 8 + 4) = a1;
        if (f == 0) {
            const float qx = newxyz[grp * 3 + 0];
            const float qy = newxyz[grp * 3 + 1];
            const float qz = newxyz[grp * 3 + 2];
            const float* xp = xyz + ((size_t)b * NPT + p) * 3;
            bufA[k * 68 + 64] = xp[0] - qx;
            bufA[k * 68 + 65] = xp[1] - qy;
            bufA[k * 68 + 66] = xp[2] - qz;
            bufA[k * 68 + 67] = 0.f;
        }
    }
    __syncthreads();

    mlp_layer<4>(bufA, wbuf, sc, bi, bufB, 17, t);
    __syncthreads();

    for (int i = t; i < 64 * 68; i += 256) {
        const int o = i / 68, c = i - o * 68;
        wbuf[i] = (c < 64) ? w1[o * 64 + c] : 0.f;
    }
    __syncthreads();

    mlp_layer<4>(bufB, wbuf, sc + 64, bi + 64, bufA, 16, t);
    __syncthreads();

    for (int i = t; i < 128 * 68; i += 256) {
        const int o = i / 68, c = i - o * 68;
        wbuf[i] = (c < 64) ? w2[o * 64 + c] : 0.f;
    }
    __syncthreads();

    mlp_layer2(bufA, wbuf, sc + 128, bi + 128, out, b, s, t);
}

// ---------------------------------------------------------------------------
extern "C" void kernel_launch(void* const* d_in, const int* in_sizes, int n_in,
                              void* d_out, int out_size, void* d_ws, size_t ws_size,
                              hipStream_t stream)
{
    const float* xyz  = (const float*)d_in[0];
    const float* feat = (const float*)d_in[1];
    const float* w0 = (const float*)d_in[2];
    const float* g0 = (const float*)d_in[3];
    const float* b0 = (const float*)d_in[4];
    const float* m0 = (const float*)d_in[5];
    const float* v0 = (const float*)d_in[6];
    const float* w1 = (const float*)d_in[7];
    const float* g1 = (const float*)d_in[8];
    const float* b1 = (const float*)d_in[9];
    const float* m1 = (const float*)d_in[10];
    const float* v1 = (const float*)d_in[11];
    const float* w2 = (const float*)d_in[12];
    const float* g2 = (const float*)d_in[13];
    const float* b2 = (const float*)d_in[14];
    const float* m2 = (const float*)d_in[15];
    const float* v2 = (const float*)d_in[16];

    float* out      = (float*)d_out;
    float* new_xyz  = out;                      // 8*512*3 = 12288 floats
    float* out_feat = out + BATCH * NQ * 3;     // 8*128*512 floats

    // workspace layout
    int*   gidx  = (int*)d_ws;                                  // 524288 B
    float* sxp   = (float*)((char*)d_ws + 524288);              // 512 KB
    float* syp   = sxp + BATCH * NPT;                           // 512 KB
    float* szp   = syp + BATCH * NPT;                           // 512 KB
    int*   sorig = (int*)(szp + BATCH * NPT);                   // 512 KB

    sort_kernel<<<BATCH, 1024, 0, stream>>>(xyz, sxp, syp, szp, sorig);
    fps_kernel<<<BATCH, 1024, 0, stream>>>(xyz, sxp, syp, szp, sorig, new_xyz);
    bq_kernel<<<(BATCH * NQ * 64) / 256, 256, 0, stream>>>(xyz, new_xyz, gidx);
    mlp_kernel<<<BATCH * NQ, 256, 0, stream>>>(xyz, feat, new_xyz, gidx,
                                               w0, g0, b0, m0, v0,
                                               w1, g1, b1, m1, v1,
                                               w2, g2, b2, m2, v2,
                                               out_feat);
}